// Round 17
// baseline (836.331 us; speedup 1.0000x reference)
//
#include <hip/hip_runtime.h>
#include <hip/hip_bf16.h>
#include <stdint.h>

typedef __attribute__((ext_vector_type(8))) short s8v;
typedef __attribute__((ext_vector_type(4))) float f4v;

#define T_TOT 8
#define NSP 32768   // T*H*W
#define K_TOT 1024
#define M_TOT 1024

__device__ __forceinline__ unsigned short f2bf(float f) {
  unsigned int u = __float_as_uint(f);
  u += 0x7FFF + ((u >> 16) & 1);   // round-to-nearest-even
  return (unsigned short)(u >> 16);
}

// ---------------------------------------------------------------------------
// Kernel 1 (dw4): depthwise 3x3x3 -> Yn8[c/8][n][c%8] (octet-blocked, n-major)
// Fix vs dw3 (95us, spilled): h-band 16->8 so held[8][2][4]=64 u32 (no
// spill), 1024 compute blocks (vs 512), ~3 blocks/CU -> 12 waves/CU.
// Slab [8t][10hr][64w] f32 = 20KB LDS; stage = 1280 float4 coalesced;
// ring compute (4-row window, 2 rows/thread); coalesced 16B {c0..c7} writes.
// bx==8 blocks do the pointwise-weight cast (fold).
// ---------------------------------------------------------------------------
__global__ __launch_bounds__(256, 3) void dw4_kernel(const float* __restrict__ X,
                                                     const float* __restrict__ DW,
                                                     unsigned short* __restrict__ Yn8,
                                                     const float* __restrict__ Wf,
                                                     unsigned short* __restrict__ Wb) {
  if (blockIdx.x == 8) {                     // castw: 128 blocks x 8192 elems
    const int base = blockIdx.y * 8192;
#pragma unroll
    for (int it = 0; it < 8; ++it) {
      const int i = base + (it * 256 + (int)threadIdx.x) * 4;
      float4 v = *(const float4*)&Wf[i];
      ushort4 o;
      o.x = f2bf(v.x); o.y = f2bf(v.y); o.z = f2bf(v.z); o.w = f2bf(v.w);
      *(ushort4*)&Wb[i] = o;
    }
    return;
  }

  __shared__ float xin[8 * 10 * 64];         // 20 KB  [t][hr][w], hr = h-(h0-1)
  const int tid = threadIdx.x;
  const int hb  = blockIdx.x;                // 0..7  (h-band of 8)
  const int cg  = blockIdx.y;                // 0..127 (channel octet)
  const int h0  = hb * 8;

  float kw[27];
#pragma unroll
  for (int j = 0; j < 27; ++j) kw[j] = DW[j];   // uniform -> scalar regs

  const int w  = tid & 63;
  const int hq = tid >> 6;                   // 0..3 -> rows hq*2, hq*2+1
  const int wl = (w == 0)  ? w : w - 1;
  const int wr = (w == 63) ? w : w + 1;
  const float* bC = &xin[(hq * 2) * 64 + w];
  const float* bL = &xin[(hq * 2) * 64 + wl];
  const float* bR = &xin[(hq * 2) * 64 + wr];

  unsigned int held[8][2][4];                // [t][j][c>>1] packed bf16 pairs

#pragma unroll
  for (int c = 0; c < 8; ++c) {
    const float* Xc = X + (size_t)(cg * 8 + c) * NSP;

    // ---- stage slab: 1280 float4, 5/thread, coalesced, h clamped+zeroed ----
#pragma unroll
    for (int i = 0; i < 5; ++i) {
      const int f  = tid + i * 256;          // 0..1279
      const int r  = f >> 4;                 // 0..79  (= t*10 + hr)
      const int wq = (f & 15) * 4;
      const int t  = r / 10;
      const int hr = r - t * 10;
      const int hg = h0 - 1 + hr;
      const int hc = min(max(hg, 0), 63);
      float4 v = *(const float4*)(Xc + (t * 64 + hc) * 64 + wq);
      if (hg != hc) v = (float4){0.f, 0.f, 0.f, 0.f};
      *(float4*)&xin[r * 64 + wq] = v;
    }
    __syncthreads();

    // ---- compute (proven ring), outputs -> held regs ----
    float a0[2], a1[2], a2[2];
#pragma unroll
    for (int j = 0; j < 2; ++j) { a0[j] = 0.f; a1[j] = 0.f; a2[j] = 0.f; }

#pragma unroll
    for (int tp = 0; tp < 8; ++tp) {
      float v[4][3];
#pragma unroll
      for (int rr = 0; rr < 4; ++rr) {       // hr = hq*2 + rr
        const int off = (tp * 10 + rr) * 64;
        float xc = bC[off];
        float xl = bL[off];
        float xr = bR[off];
        if (w == 0)  xl = 0.f;
        if (w == 63) xr = 0.f;
        v[rr][0] = xl; v[rr][1] = xc; v[rr][2] = xr;
      }
#pragma unroll
      for (int j = 0; j < 2; ++j)
#pragma unroll
        for (int kh = 0; kh < 3; ++kh)
#pragma unroll
          for (int kd = 0; kd < 3; ++kd) {
            const float xv = v[j + kh][kd];
            if (tp >= 1) a0[j] += kw[(2 * 3 + kh) * 3 + kd] * xv;
            a1[j] += kw[(1 * 3 + kh) * 3 + kd] * xv;
            if (tp <= 6) a2[j] += kw[(0 * 3 + kh) * 3 + kd] * xv;
          }
      if (tp >= 1) {
        const int to = tp - 1;
#pragma unroll
        for (int j = 0; j < 2; ++j) {
          const unsigned int b = f2bf(a0[j]);
          if (c & 1) held[to][j][c >> 1] |= (b << 16);
          else       held[to][j][c >> 1] = b;
        }
      }
#pragma unroll
      for (int j = 0; j < 2; ++j) { a0[j] = a1[j]; a1[j] = a2[j]; a2[j] = 0.f; }
    }
    {                                        // t_out = 7
#pragma unroll
      for (int j = 0; j < 2; ++j) {
        const unsigned int b = f2bf(a0[j]);
        if (c & 1) held[7][j][c >> 1] |= (b << 16);
        else       held[7][j][c >> 1] = b;
      }
    }
    __syncthreads();                         // slab reused next channel
  }

  // ---- write: 16B chunks {c0..c7} per n, 1KB contiguous per wave ----
  const size_t nb = (size_t)cg * NSP;
#pragma unroll
  for (int t = 0; t < 8; ++t)
#pragma unroll
    for (int j = 0; j < 2; ++j) {
      const int n = t * 4096 + (h0 + hq * 2 + j) * 64 + w;
      uint4 o;
      o.x = held[t][j][0]; o.y = held[t][j][1];
      o.z = held[t][j][2]; o.w = held[t][j][3];
      *(uint4*)&Yn8[(nb + (size_t)n) * 8] = o;
    }
}

// ---------------------------------------------------------------------------
// Kernel 3 (round-16 verbatim, measured ~54us): C = A * Y,
// B staged directly from Yn8[octet][n][8].  BM=BN=256, BK=64, 512 thr,
// wave-tile 128x64, acc[8][4]; LDS 128KB, proven both-sides XOR swizzle;
// v6 counted-vmcnt(4) 2-phase schedule.
// ---------------------------------------------------------------------------
__device__ __forceinline__ void gload_lds16(const void* g, void* lds) {
  __builtin_amdgcn_global_load_lds(
      (const __attribute__((address_space(1))) void*)(uintptr_t)g,
      (__attribute__((address_space(3))) void*)(uintptr_t)lds, 16, 0, 0);
}

__global__ __launch_bounds__(512, 2) void gemm8_kernel(const unsigned short* __restrict__ A,
                                                       const unsigned short* __restrict__ Yn8,
                                                       float* __restrict__ C) {
  __shared__ char smem[131072];              // 2 x {A0,A1,B0,B1} x 16KB
  const int tid  = threadIdx.x;
  const int lane = tid & 63;
  const int wid  = tid >> 6;
  const int wm   = wid >> 2, wn = wid & 3;   // 2 x 4 wave grid

  // bijective XCD remap: 512 wgs, 64 per XCD; bm fastest.
  const int wg = (int)blockIdx.x;
  const int lg = (wg & 7) * 64 + (wg >> 3);
  const int bm = lg & 3;                     // 0..3   (M/256)
  const int bn = lg >> 2;                    // 0..127 (N/256)

  f4v acc[8][4];
#pragma unroll
  for (int i = 0; i < 8; ++i)
#pragma unroll
    for (int j = 0; j < 4; ++j) acc[i][j] = (f4v){0.f, 0.f, 0.f, 0.f};

  const int r    = tid >> 2;                                 // 0..127
  const int cswz = (tid & 3) ^ ((tid >> 3) & 3);             // swizzled chunk
  const unsigned short* ga  = A + (size_t)(bm * 256 + r) * K_TOT + cswz * 8;
  const unsigned short* gbb = Yn8 + ((size_t)cswz * NSP + (size_t)(bn * 256 + r)) * 8;
  const int stg = wid * 1024;

#define STAGE_KK(nb, tt, kk)                                                  \
  do {                                                                        \
    const int ko = (tt) * 64 + (kk) * 32;                                     \
    const size_t bko = (size_t)((tt) * 8 + (kk) * 4) * NSP * 8;               \
    char* ab = smem + (nb) + (kk) * 16384 + stg;                              \
    char* bb = smem + (nb) + 32768 + (kk) * 16384 + stg;                      \
    gload_lds16(ga + ko,                 ab);                                 \
    gload_lds16(ga + 128 * K_TOT + ko,   ab + 8192);                          \
    gload_lds16(gbb + bko,               bb);                                 \
    gload_lds16(gbb + bko + 128 * 8,     bb + 8192);                          \
  } while (0)

  const int cph  = ((lane >> 4) ^ ((lane >> 1) & 3)) * 8;    // swizzled col
  const int arow = wm * 128 + (lane & 15);
  const int brow = wn * 64  + (lane & 15);

#define PHASE(cu, nx, tt, kk, pf)                                             \
  do {                                                                        \
    const unsigned short* Ac = (const unsigned short*)(smem + (cu));          \
    const unsigned short* Bc = (const unsigned short*)(smem + (cu) + 32768);  \
    s8v av[8], bv[4];                                                         \
    _Pragma("unroll")                                                         \
    for (int nf = 0; nf < 4; ++nf)                                            \
      bv[nf] = *(const s8v*)&Bc[(kk) * 8192 + (brow + nf * 16) * 32 + cph];   \
    _Pragma("unroll")                                                         \
    for (int mf = 0; mf < 8; ++mf)                                            \
      av[mf] = *(const s8v*)&Ac[(kk) * 8192 + (arow + mf * 16) * 32 + cph];   \
    if (pf) STAGE_KK(nx, (tt) + 1, kk);                                       \
    __builtin_amdgcn_s_setprio(1);                                            \
    _Pragma("unroll")                                                         \
    for (int mf = 0; mf < 8; ++mf)                                            \
      _Pragma("unroll")                                                       \
      for (int nf = 0; nf < 4; ++nf)                                          \
        acc[mf][nf] = __builtin_amdgcn_mfma_f32_16x16x32_bf16(                \
            av[mf], bv[nf], acc[mf][nf], 0, 0, 0);                            \
    __builtin_amdgcn_s_setprio(0);                                            \
  } while (0)

  // prologue: tile 0 both halves in flight (8 loads)
  STAGE_KK(0, 0, 0);
  STAGE_KK(0, 0, 1);

  for (int t = 0; t < 15; ++t) {
    const int cu = (t & 1) << 16;
    const int nx = cu ^ 65536;
    asm volatile("s_waitcnt vmcnt(4)" ::: "memory");   // t.kk0 landed; t.kk1 may fly
    __builtin_amdgcn_s_barrier();
    PHASE(cu, nx, t, 0, true);                         // issues t+1.kk0
    asm volatile("s_waitcnt vmcnt(4)" ::: "memory");   // t.kk1 landed; t+1.kk0 may fly
    __builtin_amdgcn_s_barrier();
    PHASE(cu, nx, t, 1, true);                         // issues t+1.kk1
  }
  // tail: tile 15 (buffer 1), nothing left to prefetch
  asm volatile("s_waitcnt vmcnt(0)" ::: "memory");
  __builtin_amdgcn_s_barrier();
  PHASE(65536, 0, 15, 0, false);
  PHASE(65536, 0, 15, 1, false);

#undef PHASE
#undef STAGE_KK

  const int rowq = (lane >> 4) * 4;
  const int colq = lane & 15;
#pragma unroll
  for (int mf = 0; mf < 8; ++mf) {
    const int row0 = bm * 256 + wm * 128 + mf * 16 + rowq;
#pragma unroll
    for (int nf = 0; nf < 4; ++nf) {
      const int col = bn * 256 + wn * 64 + nf * 16 + colq;
      float* cp = C + (size_t)row0 * NSP + col;
#pragma unroll
      for (int j = 0; j < 4; ++j) cp[(size_t)j * NSP] = acc[mf][nf][j];
    }
  }
}

// ---------------------------------------------------------------------------
extern "C" void kernel_launch(void* const* d_in, const int* in_sizes, int n_in,
                              void* d_out, int out_size, void* d_ws, size_t ws_size,
                              hipStream_t stream) {
  const float* feat = (const float*)d_in[0];
  const float* dw   = (const float*)d_in[1];
  const float* pw   = (const float*)d_in[2];
  float* out = (float*)d_out;

  unsigned short* Yn8 = (unsigned short*)d_ws;                // [128][32768][8] bf16, 64 MiB
  unsigned short* Wb  = Yn8 + (size_t)K_TOT * NSP;            // [1024][1024] bf16, 2 MiB

  dw4_kernel<<<dim3(9, 128), dim3(256), 0, stream>>>(feat, dw, Yn8, pw, Wb);
  gemm8_kernel<<<dim3(512), dim3(512), 0, stream>>>(Wb, Yn8, out);
}

// Round 18
// 546.737 us; speedup vs baseline: 1.5297x; 1.5297x over previous
//
#include <hip/hip_runtime.h>
#include <hip/hip_bf16.h>
#include <stdint.h>

typedef __attribute__((ext_vector_type(8))) short s8v;
typedef __attribute__((ext_vector_type(4))) float f4v;

#define T_TOT 8
#define NSP 32768   // T*H*W
#define K_TOT 1024
#define M_TOT 1024

__device__ __forceinline__ unsigned short f2bf(float f) {
  unsigned int u = __float_as_uint(f);
  u += 0x7FFF + ((u >> 16) & 1);   // round-to-nearest-even
  return (unsigned short)(u >> 16);
}

// ---------------------------------------------------------------------------
// Kernel 1 (dw5): depthwise 3x3x3 -> Yn8[c/8][n][c%8] (octet-blocked).
// = dw4 (h-band 8, 1024 compute blocks) but with __launch_bounds__(256,2):
// round-16/17 A/B showed (256,2) lets the allocator keep held[] in the
// unified VGPR/AGPR file (dw3: WRITE 67.5MB clean), while (256,3) capped
// VGPR at 84 and spilled held to scratch (dw4: WRITE 1.2GB, 772us).
// Slab [8t][10hr][64w] f32 = 20KB LDS; stage = 1280 float4 coalesced;
// ring compute (4-row window, 2 rows/thread); coalesced 16B {c0..c7} writes.
// bx==8 blocks do the pointwise-weight cast (fold).
// ---------------------------------------------------------------------------
__global__ __launch_bounds__(256, 2) void dw5_kernel(const float* __restrict__ X,
                                                     const float* __restrict__ DW,
                                                     unsigned short* __restrict__ Yn8,
                                                     const float* __restrict__ Wf,
                                                     unsigned short* __restrict__ Wb) {
  if (blockIdx.x == 8) {                     // castw: 128 blocks x 8192 elems
    const int base = blockIdx.y * 8192;
#pragma unroll
    for (int it = 0; it < 8; ++it) {
      const int i = base + (it * 256 + (int)threadIdx.x) * 4;
      float4 v = *(const float4*)&Wf[i];
      ushort4 o;
      o.x = f2bf(v.x); o.y = f2bf(v.y); o.z = f2bf(v.z); o.w = f2bf(v.w);
      *(ushort4*)&Wb[i] = o;
    }
    return;
  }

  __shared__ float xin[8 * 10 * 64];         // 20 KB  [t][hr][w], hr = h-(h0-1)
  const int tid = threadIdx.x;
  const int hb  = blockIdx.x;                // 0..7  (h-band of 8)
  const int cg  = blockIdx.y;                // 0..127 (channel octet)
  const int h0  = hb * 8;

  float kw[27];
#pragma unroll
  for (int j = 0; j < 27; ++j) kw[j] = DW[j];   // uniform -> scalar regs

  const int w  = tid & 63;
  const int hq = tid >> 6;                   // 0..3 -> rows hq*2, hq*2+1
  const int wl = (w == 0)  ? w : w - 1;
  const int wr = (w == 63) ? w : w + 1;
  const float* bC = &xin[(hq * 2) * 64 + w];
  const float* bL = &xin[(hq * 2) * 64 + wl];
  const float* bR = &xin[(hq * 2) * 64 + wr];

  unsigned int held[8][2][4];                // [t][j][c>>1] packed bf16 pairs

#pragma unroll
  for (int c = 0; c < 8; ++c) {
    const float* Xc = X + (size_t)(cg * 8 + c) * NSP;

    // ---- stage slab: 1280 float4, 5/thread, coalesced, h clamped+zeroed ----
#pragma unroll
    for (int i = 0; i < 5; ++i) {
      const int f  = tid + i * 256;          // 0..1279
      const int r  = f >> 4;                 // 0..79  (= t*10 + hr)
      const int wq = (f & 15) * 4;
      const int t  = r / 10;
      const int hr = r - t * 10;
      const int hg = h0 - 1 + hr;
      const int hc = min(max(hg, 0), 63);
      float4 v = *(const float4*)(Xc + (t * 64 + hc) * 64 + wq);
      if (hg != hc) v = (float4){0.f, 0.f, 0.f, 0.f};
      *(float4*)&xin[r * 64 + wq] = v;
    }
    __syncthreads();

    // ---- compute (proven ring), outputs -> held regs ----
    float a0[2], a1[2], a2[2];
#pragma unroll
    for (int j = 0; j < 2; ++j) { a0[j] = 0.f; a1[j] = 0.f; a2[j] = 0.f; }

#pragma unroll
    for (int tp = 0; tp < 8; ++tp) {
      float v[4][3];
#pragma unroll
      for (int rr = 0; rr < 4; ++rr) {       // hr = hq*2 + rr
        const int off = (tp * 10 + rr) * 64;
        float xc = bC[off];
        float xl = bL[off];
        float xr = bR[off];
        if (w == 0)  xl = 0.f;
        if (w == 63) xr = 0.f;
        v[rr][0] = xl; v[rr][1] = xc; v[rr][2] = xr;
      }
#pragma unroll
      for (int j = 0; j < 2; ++j)
#pragma unroll
        for (int kh = 0; kh < 3; ++kh)
#pragma unroll
          for (int kd = 0; kd < 3; ++kd) {
            const float xv = v[j + kh][kd];
            if (tp >= 1) a0[j] += kw[(2 * 3 + kh) * 3 + kd] * xv;
            a1[j] += kw[(1 * 3 + kh) * 3 + kd] * xv;
            if (tp <= 6) a2[j] += kw[(0 * 3 + kh) * 3 + kd] * xv;
          }
      if (tp >= 1) {
        const int to = tp - 1;
#pragma unroll
        for (int j = 0; j < 2; ++j) {
          const unsigned int b = f2bf(a0[j]);
          if (c & 1) held[to][j][c >> 1] |= (b << 16);
          else       held[to][j][c >> 1] = b;
        }
      }
#pragma unroll
      for (int j = 0; j < 2; ++j) { a0[j] = a1[j]; a1[j] = a2[j]; a2[j] = 0.f; }
    }
    {                                        // t_out = 7
#pragma unroll
      for (int j = 0; j < 2; ++j) {
        const unsigned int b = f2bf(a0[j]);
        if (c & 1) held[7][j][c >> 1] |= (b << 16);
        else       held[7][j][c >> 1] = b;
      }
    }
    __syncthreads();                         // slab reused next channel
  }

  // ---- write: 16B chunks {c0..c7} per n, 1KB contiguous per wave ----
  const size_t nb = (size_t)cg * NSP;
#pragma unroll
  for (int t = 0; t < 8; ++t)
#pragma unroll
    for (int j = 0; j < 2; ++j) {
      const int n = t * 4096 + (h0 + hq * 2 + j) * 64 + w;
      uint4 o;
      o.x = held[t][j][0]; o.y = held[t][j][1];
      o.z = held[t][j][2]; o.w = held[t][j][3];
      *(uint4*)&Yn8[(nb + (size_t)n) * 8] = o;
    }
}

// ---------------------------------------------------------------------------
// Kernel 3 (round-16 verbatim, measured ~54us): C = A * Y,
// B staged directly from Yn8[octet][n][8].  BM=BN=256, BK=64, 512 thr,
// wave-tile 128x64, acc[8][4]; LDS 128KB, proven both-sides XOR swizzle;
// v6 counted-vmcnt(4) 2-phase schedule.
// ---------------------------------------------------------------------------
__device__ __forceinline__ void gload_lds16(const void* g, void* lds) {
  __builtin_amdgcn_global_load_lds(
      (const __attribute__((address_space(1))) void*)(uintptr_t)g,
      (__attribute__((address_space(3))) void*)(uintptr_t)lds, 16, 0, 0);
}

__global__ __launch_bounds__(512, 2) void gemm8_kernel(const unsigned short* __restrict__ A,
                                                       const unsigned short* __restrict__ Yn8,
                                                       float* __restrict__ C) {
  __shared__ char smem[131072];              // 2 x {A0,A1,B0,B1} x 16KB
  const int tid  = threadIdx.x;
  const int lane = tid & 63;
  const int wid  = tid >> 6;
  const int wm   = wid >> 2, wn = wid & 3;   // 2 x 4 wave grid

  // bijective XCD remap: 512 wgs, 64 per XCD; bm fastest.
  const int wg = (int)blockIdx.x;
  const int lg = (wg & 7) * 64 + (wg >> 3);
  const int bm = lg & 3;                     // 0..3   (M/256)
  const int bn = lg >> 2;                    // 0..127 (N/256)

  f4v acc[8][4];
#pragma unroll
  for (int i = 0; i < 8; ++i)
#pragma unroll
    for (int j = 0; j < 4; ++j) acc[i][j] = (f4v){0.f, 0.f, 0.f, 0.f};

  const int r    = tid >> 2;                                 // 0..127
  const int cswz = (tid & 3) ^ ((tid >> 3) & 3);             // swizzled chunk
  const unsigned short* ga  = A + (size_t)(bm * 256 + r) * K_TOT + cswz * 8;
  const unsigned short* gbb = Yn8 + ((size_t)cswz * NSP + (size_t)(bn * 256 + r)) * 8;
  const int stg = wid * 1024;

#define STAGE_KK(nb, tt, kk)                                                  \
  do {                                                                        \
    const int ko = (tt) * 64 + (kk) * 32;                                     \
    const size_t bko = (size_t)((tt) * 8 + (kk) * 4) * NSP * 8;               \
    char* ab = smem + (nb) + (kk) * 16384 + stg;                              \
    char* bb = smem + (nb) + 32768 + (kk) * 16384 + stg;                      \
    gload_lds16(ga + ko,                 ab);                                 \
    gload_lds16(ga + 128 * K_TOT + ko,   ab + 8192);                          \
    gload_lds16(gbb + bko,               bb);                                 \
    gload_lds16(gbb + bko + 128 * 8,     bb + 8192);                          \
  } while (0)

  const int cph  = ((lane >> 4) ^ ((lane >> 1) & 3)) * 8;    // swizzled col
  const int arow = wm * 128 + (lane & 15);
  const int brow = wn * 64  + (lane & 15);

#define PHASE(cu, nx, tt, kk, pf)                                             \
  do {                                                                        \
    const unsigned short* Ac = (const unsigned short*)(smem + (cu));          \
    const unsigned short* Bc = (const unsigned short*)(smem + (cu) + 32768);  \
    s8v av[8], bv[4];                                                         \
    _Pragma("unroll")                                                         \
    for (int nf = 0; nf < 4; ++nf)                                            \
      bv[nf] = *(const s8v*)&Bc[(kk) * 8192 + (brow + nf * 16) * 32 + cph];   \
    _Pragma("unroll")                                                         \
    for (int mf = 0; mf < 8; ++mf)                                            \
      av[mf] = *(const s8v*)&Ac[(kk) * 8192 + (arow + mf * 16) * 32 + cph];   \
    if (pf) STAGE_KK(nx, (tt) + 1, kk);                                       \
    __builtin_amdgcn_s_setprio(1);                                            \
    _Pragma("unroll")                                                         \
    for (int mf = 0; mf < 8; ++mf)                                            \
      _Pragma("unroll")                                                       \
      for (int nf = 0; nf < 4; ++nf)                                          \
        acc[mf][nf] = __builtin_amdgcn_mfma_f32_16x16x32_bf16(                \
            av[mf], bv[nf], acc[mf][nf], 0, 0, 0);                            \
    __builtin_amdgcn_s_setprio(0);                                            \
  } while (0)

  // prologue: tile 0 both halves in flight (8 loads)
  STAGE_KK(0, 0, 0);
  STAGE_KK(0, 0, 1);

  for (int t = 0; t < 15; ++t) {
    const int cu = (t & 1) << 16;
    const int nx = cu ^ 65536;
    asm volatile("s_waitcnt vmcnt(4)" ::: "memory");   // t.kk0 landed; t.kk1 may fly
    __builtin_amdgcn_s_barrier();
    PHASE(cu, nx, t, 0, true);                         // issues t+1.kk0
    asm volatile("s_waitcnt vmcnt(4)" ::: "memory");   // t.kk1 landed; t+1.kk0 may fly
    __builtin_amdgcn_s_barrier();
    PHASE(cu, nx, t, 1, true);                         // issues t+1.kk1
  }
  // tail: tile 15 (buffer 1), nothing left to prefetch
  asm volatile("s_waitcnt vmcnt(0)" ::: "memory");
  __builtin_amdgcn_s_barrier();
  PHASE(65536, 0, 15, 0, false);
  PHASE(65536, 0, 15, 1, false);

#undef PHASE
#undef STAGE_KK

  const int rowq = (lane >> 4) * 4;
  const int colq = lane & 15;
#pragma unroll
  for (int mf = 0; mf < 8; ++mf) {
    const int row0 = bm * 256 + wm * 128 + mf * 16 + rowq;
#pragma unroll
    for (int nf = 0; nf < 4; ++nf) {
      const int col = bn * 256 + wn * 64 + nf * 16 + colq;
      float* cp = C + (size_t)row0 * NSP + col;
#pragma unroll
      for (int j = 0; j < 4; ++j) cp[(size_t)j * NSP] = acc[mf][nf][j];
    }
  }
}

// ---------------------------------------------------------------------------
extern "C" void kernel_launch(void* const* d_in, const int* in_sizes, int n_in,
                              void* d_out, int out_size, void* d_ws, size_t ws_size,
                              hipStream_t stream) {
  const float* feat = (const float*)d_in[0];
  const float* dw   = (const float*)d_in[1];
  const float* pw   = (const float*)d_in[2];
  float* out = (float*)d_out;

  unsigned short* Yn8 = (unsigned short*)d_ws;                // [128][32768][8] bf16, 64 MiB
  unsigned short* Wb  = Yn8 + (size_t)K_TOT * NSP;            // [1024][1024] bf16, 2 MiB

  dw5_kernel<<<dim3(9, 128), dim3(256), 0, stream>>>(feat, dw, Yn8, pw, Wb);
  gemm8_kernel<<<dim3(512), dim3(512), 0, stream>>>(Wb, Yn8, out);
}

// Round 19
// 149.357 us; speedup vs baseline: 5.5995x; 3.6606x over previous
//
#include <hip/hip_runtime.h>
#include <hip/hip_bf16.h>
#include <stdint.h>

typedef __attribute__((ext_vector_type(8))) short s8v;
typedef __attribute__((ext_vector_type(4))) float f4v;

#define T_TOT 8
#define NSP 32768   // T*H*W
#define K_TOT 1024
#define M_TOT 1024

__device__ __forceinline__ unsigned short f2bf(float f) {
  unsigned int u = __float_as_uint(f);
  u += 0x7FFF + ((u >> 16) & 1);   // round-to-nearest-even
  return (unsigned short)(u >> 16);
}

// ---------------------------------------------------------------------------
// Kernel 1 (round-15 verbatim, proven ~40-50us clean): depthwise 3x3x3 ->
// Yn[c][n] (n-major per channel).  bx==4 blocks cast pw weight (fold).
// ---------------------------------------------------------------------------
__global__ __launch_bounds__(256) void dw_kernel(const float* __restrict__ X,
                                                 const float* __restrict__ DW,
                                                 unsigned short* __restrict__ Yn,
                                                 const float* __restrict__ Wf,
                                                 unsigned short* __restrict__ Wb) {
  if (blockIdx.x == 4) {                     // castw branch: 1024 elems/block
    const int i = (blockIdx.y * 256 + threadIdx.x) * 4;
    float4 v = *(const float4*)&Wf[i];
    ushort4 o;
    o.x = f2bf(v.x); o.y = f2bf(v.y); o.z = f2bf(v.z); o.w = f2bf(v.w);
    *(ushort4*)&Wb[i] = o;
    return;
  }

  __shared__ float xin[8 * 18 * 64];         // 36 KB  [t][hr][w]
  const int tid = threadIdx.x;
  const int hb  = blockIdx.x;                // 0..3
  const int c   = blockIdx.y;                // 0..1023
  const int h0  = hb * 16;

  float kw[27];
#pragma unroll
  for (int j = 0; j < 27; ++j) kw[j] = DW[j];

  const float* Xc = X + (size_t)c * NSP;

#pragma unroll
  for (int i = 0; i < 9; ++i) {
    const int f  = tid + i * 256;
    const int r  = f >> 4;
    const int wq = (f & 15) * 4;
    const int t  = r / 18;
    const int hr = r - t * 18;
    const int hg = h0 - 1 + hr;
    const int hc = min(max(hg, 0), 63);
    float4 v = *(const float4*)(Xc + (t * 64 + hc) * 64 + wq);
    if (hg != hc) v = (float4){0.f, 0.f, 0.f, 0.f};
    *(float4*)&xin[r * 64 + wq] = v;
  }
  __syncthreads();

  const int w  = tid & 63;
  const int hq = tid >> 6;
  const int wl = (w == 0)  ? w : w - 1;
  const int wr = (w == 63) ? w : w + 1;
  const float* bC = &xin[(hq * 4) * 64 + w];
  const float* bL = &xin[(hq * 4) * 64 + wl];
  const float* bR = &xin[(hq * 4) * 64 + wr];
  unsigned short* Yb = Yn + (size_t)c * NSP + (h0 + hq * 4) * 64 + w;

  float a0[4], a1[4], a2[4];
#pragma unroll
  for (int j = 0; j < 4; ++j) { a0[j] = 0.f; a1[j] = 0.f; a2[j] = 0.f; }

#pragma unroll
  for (int tp = 0; tp < 8; ++tp) {
    float v[6][3];
#pragma unroll
    for (int rr = 0; rr < 6; ++rr) {
      const int off = (tp * 18 + rr) * 64;
      float xc = bC[off];
      float xl = bL[off];
      float xr = bR[off];
      if (w == 0)  xl = 0.f;
      if (w == 63) xr = 0.f;
      v[rr][0] = xl; v[rr][1] = xc; v[rr][2] = xr;
    }
#pragma unroll
    for (int j = 0; j < 4; ++j)
#pragma unroll
      for (int kh = 0; kh < 3; ++kh)
#pragma unroll
        for (int kd = 0; kd < 3; ++kd) {
          const float xv = v[j + kh][kd];
          if (tp >= 1) a0[j] += kw[(2 * 3 + kh) * 3 + kd] * xv;
          a1[j] += kw[(1 * 3 + kh) * 3 + kd] * xv;
          if (tp <= 6) a2[j] += kw[(0 * 3 + kh) * 3 + kd] * xv;
        }
    if (tp >= 1) {
      unsigned short* yp = Yb + (size_t)(tp - 1) * 4096;
#pragma unroll
      for (int j = 0; j < 4; ++j) yp[j * 64] = f2bf(a0[j]);
    }
#pragma unroll
    for (int j = 0; j < 4; ++j) { a0[j] = a1[j]; a1[j] = a2[j]; a2[j] = 0.f; }
  }
  {
    unsigned short* yp = Yb + (size_t)7 * 4096;
#pragma unroll
    for (int j = 0; j < 4; ++j) yp[j * 64] = f2bf(a0[j]);
  }
}

// ---------------------------------------------------------------------------
// Kernel 1b (tr8): octet-interleave Yn[c][n] -> Yn8[c/8][n][c%8].
// Block = 8 channels x 1024 n.  Stage 16KB via full-line uint4 loads into
// LDS pitch 1032 u16 (rows 16B-aligned; gather bank = row*4+(n>>1):
// 8 rows distinct banks, 2 lanes/bank = free).  Write packs {c0..c7} as
// uint4 -> 4KB contiguous per wave-iter.  128MB moved -> ~21us.
// ---------------------------------------------------------------------------
__global__ __launch_bounds__(256) void tr8_kernel(const unsigned short* __restrict__ Yn,
                                                  unsigned short* __restrict__ Yn8) {
  __shared__ unsigned short tb[8][1032];     // 16.1 KB
  const int tid = threadIdx.x;
  const int n0  = blockIdx.x * 1024;
  const int cg  = blockIdx.y;                // 0..127

#pragma unroll
  for (int i = 0; i < 4; ++i) {
    const int f   = tid + i * 256;           // 0..1023
    const int row = f >> 7;                  // 0..7
    const int col = (f & 127) * 8;           // u16 offset in row
    const uint4 v = *(const uint4*)&Yn[(size_t)(cg * 8 + row) * NSP + n0 + col];
    *(uint4*)&tb[row][col] = v;
  }
  __syncthreads();

#pragma unroll
  for (int i = 0; i < 4; ++i) {
    const int n = tid + i * 256;             // 0..1023
    uint4 o;
    o.x = (unsigned)tb[0][n] | ((unsigned)tb[1][n] << 16);
    o.y = (unsigned)tb[2][n] | ((unsigned)tb[3][n] << 16);
    o.z = (unsigned)tb[4][n] | ((unsigned)tb[5][n] << 16);
    o.w = (unsigned)tb[6][n] | ((unsigned)tb[7][n] << 16);
    *(uint4*)&Yn8[((size_t)cg * NSP + n0 + n) * 8] = o;
  }
}

// ---------------------------------------------------------------------------
// Kernel 3 (round-16 verbatim, measured ~54us): C = A * Y,
// B staged directly from Yn8[octet][n][8].  BM=BN=256, BK=64, 512 thr,
// wave-tile 128x64, acc[8][4]; LDS 128KB, proven both-sides XOR swizzle;
// v6 counted-vmcnt(4) 2-phase schedule.
// ---------------------------------------------------------------------------
__device__ __forceinline__ void gload_lds16(const void* g, void* lds) {
  __builtin_amdgcn_global_load_lds(
      (const __attribute__((address_space(1))) void*)(uintptr_t)g,
      (__attribute__((address_space(3))) void*)(uintptr_t)lds, 16, 0, 0);
}

__global__ __launch_bounds__(512, 2) void gemm8_kernel(const unsigned short* __restrict__ A,
                                                       const unsigned short* __restrict__ Yn8,
                                                       float* __restrict__ C) {
  __shared__ char smem[131072];              // 2 x {A0,A1,B0,B1} x 16KB
  const int tid  = threadIdx.x;
  const int lane = tid & 63;
  const int wid  = tid >> 6;
  const int wm   = wid >> 2, wn = wid & 3;   // 2 x 4 wave grid

  // bijective XCD remap: 512 wgs, 64 per XCD; bm fastest.
  const int wg = (int)blockIdx.x;
  const int lg = (wg & 7) * 64 + (wg >> 3);
  const int bm = lg & 3;                     // 0..3   (M/256)
  const int bn = lg >> 2;                    // 0..127 (N/256)

  f4v acc[8][4];
#pragma unroll
  for (int i = 0; i < 8; ++i)
#pragma unroll
    for (int j = 0; j < 4; ++j) acc[i][j] = (f4v){0.f, 0.f, 0.f, 0.f};

  const int r    = tid >> 2;                                 // 0..127
  const int cswz = (tid & 3) ^ ((tid >> 3) & 3);             // swizzled chunk
  const unsigned short* ga  = A + (size_t)(bm * 256 + r) * K_TOT + cswz * 8;
  const unsigned short* gbb = Yn8 + ((size_t)cswz * NSP + (size_t)(bn * 256 + r)) * 8;
  const int stg = wid * 1024;

#define STAGE_KK(nb, tt, kk)                                                  \
  do {                                                                        \
    const int ko = (tt) * 64 + (kk) * 32;                                     \
    const size_t bko = (size_t)((tt) * 8 + (kk) * 4) * NSP * 8;               \
    char* ab = smem + (nb) + (kk) * 16384 + stg;                              \
    char* bb = smem + (nb) + 32768 + (kk) * 16384 + stg;                      \
    gload_lds16(ga + ko,                 ab);                                 \
    gload_lds16(ga + 128 * K_TOT + ko,   ab + 8192);                          \
    gload_lds16(gbb + bko,               bb);                                 \
    gload_lds16(gbb + bko + 128 * 8,     bb + 8192);                          \
  } while (0)

  const int cph  = ((lane >> 4) ^ ((lane >> 1) & 3)) * 8;    // swizzled col
  const int arow = wm * 128 + (lane & 15);
  const int brow = wn * 64  + (lane & 15);

#define PHASE(cu, nx, tt, kk, pf)                                             \
  do {                                                                        \
    const unsigned short* Ac = (const unsigned short*)(smem + (cu));          \
    const unsigned short* Bc = (const unsigned short*)(smem + (cu) + 32768);  \
    s8v av[8], bv[4];                                                         \
    _Pragma("unroll")                                                         \
    for (int nf = 0; nf < 4; ++nf)                                            \
      bv[nf] = *(const s8v*)&Bc[(kk) * 8192 + (brow + nf * 16) * 32 + cph];   \
    _Pragma("unroll")                                                         \
    for (int mf = 0; mf < 8; ++mf)                                            \
      av[mf] = *(const s8v*)&Ac[(kk) * 8192 + (arow + mf * 16) * 32 + cph];   \
    if (pf) STAGE_KK(nx, (tt) + 1, kk);                                       \
    __builtin_amdgcn_s_setprio(1);                                            \
    _Pragma("unroll")                                                         \
    for (int mf = 0; mf < 8; ++mf)                                            \
      _Pragma("unroll")                                                       \
      for (int nf = 0; nf < 4; ++nf)                                          \
        acc[mf][nf] = __builtin_amdgcn_mfma_f32_16x16x32_bf16(                \
            av[mf], bv[nf], acc[mf][nf], 0, 0, 0);                            \
    __builtin_amdgcn_s_setprio(0);                                            \
  } while (0)

  // prologue: tile 0 both halves in flight (8 loads)
  STAGE_KK(0, 0, 0);
  STAGE_KK(0, 0, 1);

  for (int t = 0; t < 15; ++t) {
    const int cu = (t & 1) << 16;
    const int nx = cu ^ 65536;
    asm volatile("s_waitcnt vmcnt(4)" ::: "memory");   // t.kk0 landed; t.kk1 may fly
    __builtin_amdgcn_s_barrier();
    PHASE(cu, nx, t, 0, true);                         // issues t+1.kk0
    asm volatile("s_waitcnt vmcnt(4)" ::: "memory");   // t.kk1 landed; t+1.kk0 may fly
    __builtin_amdgcn_s_barrier();
    PHASE(cu, nx, t, 1, true);                         // issues t+1.kk1
  }
  // tail: tile 15 (buffer 1), nothing left to prefetch
  asm volatile("s_waitcnt vmcnt(0)" ::: "memory");
  __builtin_amdgcn_s_barrier();
  PHASE(65536, 0, 15, 0, false);
  PHASE(65536, 0, 15, 1, false);

#undef PHASE
#undef STAGE_KK

  const int rowq = (lane >> 4) * 4;
  const int colq = lane & 15;
#pragma unroll
  for (int mf = 0; mf < 8; ++mf) {
    const int row0 = bm * 256 + wm * 128 + mf * 16 + rowq;
#pragma unroll
    for (int nf = 0; nf < 4; ++nf) {
      const int col = bn * 256 + wn * 64 + nf * 16 + colq;
      float* cp = C + (size_t)row0 * NSP + col;
#pragma unroll
      for (int j = 0; j < 4; ++j) cp[(size_t)j * NSP] = acc[mf][nf][j];
    }
  }
}

// ---------------------------------------------------------------------------
// Fallback GEMM (round-3 verbatim): consumes Yn[k][n] directly.
// ---------------------------------------------------------------------------
__global__ __launch_bounds__(256) void gemm_nmajor_kernel(const unsigned short* __restrict__ A,
                                                          const unsigned short* __restrict__ B,
                                                          float* __restrict__ C) {
  __shared__ unsigned short As[128][32];
  __shared__ unsigned short Bs[128][40];
  const int tid  = threadIdx.x;
  const int lane = tid & 63;
  const int wv   = tid >> 6;
  const int wr   = wv >> 1, wc = wv & 1;
  const int bn   = blockIdx.x, bm = blockIdx.y;
  const int n0   = bn * 128;

  f4v acc[4][4];
#pragma unroll
  for (int i = 0; i < 4; ++i)
#pragma unroll
    for (int j = 0; j < 4; ++j) acc[i][j] = (f4v){0.f, 0.f, 0.f, 0.f};

  const int r  = tid >> 2;
  const int kb = (tid & 3) * 8;
  const unsigned short* ga0 = A + (size_t)(bm * 128 + r) * K_TOT + kb;
  char* ldsA = (char*)(&As[0][0]) + wv * 1024;
  const int nq4 = (tid >> 3) * 4;
  const int kq4 = (tid & 7) * 4;

  for (int kt = 0; kt < K_TOT; kt += 32) {
    __syncthreads();
    gload_lds16(ga0 + kt,               ldsA);
    gload_lds16(ga0 + 64 * K_TOT + kt,  ldsA + 4096);

    const unsigned short* gB = B + (size_t)(kt + kq4) * NSP + n0 + nq4;
    uint2 L0 = *(const uint2*)(gB);
    uint2 L1 = *(const uint2*)(gB + NSP);
    uint2 L2 = *(const uint2*)(gB + 2 * NSP);
    uint2 L3 = *(const uint2*)(gB + 3 * NSP);
    uint2 W0, W1, W2, W3;
    W0.x = (L0.x & 0xFFFFu) | (L1.x << 16);
    W0.y = (L2.x & 0xFFFFu) | (L3.x << 16);
    W1.x = (L0.x >> 16) | (L1.x & 0xFFFF0000u);
    W1.y = (L2.x >> 16) | (L3.x & 0xFFFF0000u);
    W2.x = (L0.y & 0xFFFFu) | (L1.y << 16);
    W2.y = (L2.y & 0xFFFFu) | (L3.y << 16);
    W3.x = (L0.y >> 16) | (L1.y & 0xFFFF0000u);
    W3.y = (L2.y >> 16) | (L3.y & 0xFFFF0000u);
    *(uint2*)&Bs[nq4 + 0][kq4] = W0;
    *(uint2*)&Bs[nq4 + 1][kq4] = W1;
    *(uint2*)&Bs[nq4 + 2][kq4] = W2;
    *(uint2*)&Bs[nq4 + 3][kq4] = W3;
    __syncthreads();

    s8v a[4], b[4];
#pragma unroll
    for (int mf = 0; mf < 4; ++mf)
      a[mf] = *(const s8v*)&As[wr * 64 + mf * 16 + (lane & 15)][(lane >> 4) * 8];
#pragma unroll
    for (int nf = 0; nf < 4; ++nf)
      b[nf] = *(const s8v*)&Bs[wc * 64 + nf * 16 + (lane & 15)][(lane >> 4) * 8];
#pragma unroll
    for (int mf = 0; mf < 4; ++mf)
#pragma unroll
      for (int nf = 0; nf < 4; ++nf)
        acc[mf][nf] = __builtin_amdgcn_mfma_f32_16x16x32_bf16(a[mf], b[nf], acc[mf][nf], 0, 0, 0);
  }

  const int rowq = (lane >> 4) * 4;
  const int colq = lane & 15;
#pragma unroll
  for (int mf = 0; mf < 4; ++mf) {
    const int row0 = bm * 128 + wr * 64 + mf * 16 + rowq;
#pragma unroll
    for (int nf = 0; nf < 4; ++nf) {
      const int col = n0 + wc * 64 + nf * 16 + colq;
      float* cp = C + (size_t)row0 * NSP + col;
#pragma unroll
      for (int j = 0; j < 4; ++j) cp[(size_t)j * NSP] = acc[mf][nf][j];
    }
  }
}

// ---------------------------------------------------------------------------
extern "C" void kernel_launch(void* const* d_in, const int* in_sizes, int n_in,
                              void* d_out, int out_size, void* d_ws, size_t ws_size,
                              hipStream_t stream) {
  const float* feat = (const float*)d_in[0];
  const float* dw   = (const float*)d_in[1];
  const float* pw   = (const float*)d_in[2];
  float* out = (float*)d_out;

  const size_t YBYTES = (size_t)K_TOT * NSP * 2;   // 64 MiB
  const size_t WBYTES = (size_t)M_TOT * K_TOT * 2; // 2 MiB

  if (ws_size >= 2 * YBYTES + WBYTES) {
    // main path (130 MiB, proven available): Yn@0, Yn8@64MiB, Wb@128MiB
    unsigned short* Yn  = (unsigned short*)d_ws;
    unsigned short* Yn8 = (unsigned short*)((char*)d_ws + YBYTES);
    unsigned short* Wb  = (unsigned short*)((char*)d_ws + 2 * YBYTES);
    dw_kernel<<<dim3(5, 1024), dim3(256), 0, stream>>>(feat, dw, Yn, pw, Wb);
    tr8_kernel<<<dim3(32, 128), dim3(256), 0, stream>>>(Yn, Yn8);
    gemm8_kernel<<<dim3(512), dim3(512), 0, stream>>>(Wb, Yn8, out);
  } else {
    // fallback (66 MiB, proven round-3 path): Yn@0, Wb@64MiB
    unsigned short* Yn = (unsigned short*)d_ws;
    unsigned short* Wb = Yn + (size_t)K_TOT * NSP;
    dw_kernel<<<dim3(5, 1024), dim3(256), 0, stream>>>(feat, dw, Yn, pw, Wb);
    gemm_nmajor_kernel<<<dim3(256, 8), dim3(256), 0, stream>>>(Wb, Yn, out);
  }
}